// Round 18
// baseline (48.121 us; speedup 1.0000x reference)
//
#include <hip/hip_runtime.h>
#include <math.h>

#define BS 8
#define NPTS 1024
#define NH 8
#define FIN 256
#define FOUT 64

typedef __attribute__((ext_vector_type(8))) short s8v;       // 8 bf16
typedef __attribute__((ext_vector_type(8))) _Float16 h8v;    // 8 f16
typedef __attribute__((ext_vector_type(2))) __fp16 fp16x2;   // cvt_pkrtz result
typedef __attribute__((ext_vector_type(4))) float f4v;       // 4 f32 acc
typedef unsigned long long u64;

__device__ __forceinline__ unsigned short f2bf(float f) {
  unsigned u = __float_as_uint(f);
  return (unsigned short)((u + 0x7fffu + ((u >> 16) & 1u)) >> 16);
}
__device__ __forceinline__ float bf2f(unsigned short s) {
  return __uint_as_float(((unsigned)s) << 16);
}
__device__ __forceinline__ float fast_tanh(float x) {
  float e = __expf(2.f * x);
  return 1.f - 2.f / (e + 1.f);
}
__device__ __forceinline__ float hw_exp2(float x) {   // D = 2^x (v_exp_f32)
  float r;
  asm("v_exp_f32 %0, %1" : "=v"(r) : "v"(x));
  return r;
}

// async global->LDS DMA, 16B per lane; LDS dest = wave-uniform base + lane*16
__device__ __forceinline__ void gl_lds16(const void* g, void* l) {
  __builtin_amdgcn_global_load_lds(
      (const __attribute__((address_space(1))) unsigned*)g,
      (__attribute__((address_space(3))) unsigned*)l, 16, 0, 0);
}

// ---------------------------------------------------------------------------
// wsplit: w -> wT_hi/lo bf16 split ([h][o][k]) — proj's only prerequisite.
// ---------------------------------------------------------------------------
__global__ __launch_bounds__(256) void wsplit_kernel(
    const float* __restrict__ w,
    unsigned short* __restrict__ wT_hi, unsigned short* __restrict__ wT_lo)
{
  const int blk = blockIdx.x;       // 0..63
  const int t = threadIdx.x;
  const int hh = blk >> 3, ks = blk & 7;
  const int o = t & 63, kq = t >> 6;
#pragma unroll
  for (int e = 0; e < 8; ++e) {
    int k = ks * 32 + kq * 8 + e;
    float v = w[((size_t)hh * FIN + k) * FOUT + o];
    unsigned short hi = f2bf(v);
    wT_hi[((size_t)hh * FOUT + o) * FIN + k] = hi;
    wT_lo[((size_t)hh * FOUT + o) * FIN + k] = f2bf(v - bf2f(hi));
  }
}

// ---------------------------------------------------------------------------
// projpack: blocks 0..1023 = projection (MFMA, counted-vmcnt ring, frozen);
//           blocks 1024..3071 = adj -> bitmask pack (HBM-bound, independent).
// The two populations overlap in one dispatch: adj's 33.5 MB HBM read hides
// under proj's compute instead of serializing as a separate kernel.
// ---------------------------------------------------------------------------
union ProjSmem {
  unsigned short Bbuf[3][4096];   // 3 x 8KB: [hi 2048 el | lo 2048 el]
  float tile[64][65];             // epilogue transpose (reused storage)
  int badsh;                      // adj-pack dtype-detect flag
};

__global__ __launch_bounds__(256, 4) void projpack_kernel(
    const float* __restrict__ h, const void* __restrict__ adjv,
    const unsigned short* __restrict__ wT_hi, const unsigned short* __restrict__ wT_lo,
    const float* __restrict__ a_src, const float* __restrict__ a_dst,
    u64* __restrict__ abits, unsigned short* __restrict__ hfrag,
    float* __restrict__ srcb, float* __restrict__ dstb)
{
  __shared__ ProjSmem sm;
  const int t = threadIdx.x;
  const int blkAll = blockIdx.x;

  if (blkAll >= 1024) {
    // ---------------- adj -> bitmask pack (frozen logic) ----------------
    const int blk = blkAll - 1024;          // 0..2047
    if (t == 0) sm.badsh = 0;
    __syncthreads();
    if (((const unsigned*)adjv)[t] > 1u) sm.badsh = 1;   // dtype detect
    __syncthreads();
    const int badsh = sm.badsh;
    const int lane = t & 63;
    const int gw = blk * 4 + (t >> 6);      // row id 0..8191
    const int b = gw >> 10, i = gw & 1023;
    const int m16 = lane & 15, g = lane >> 4;
    u64 words[4];
    if (badsh == 0) {                       // int32 {0,1} adjacency
      const int4* row4 = (const int4*)((const int*)adjv + ((size_t)b * NPTS + i) * NPTS);
      int4 av[4];
      av[0] = row4[lane]; av[1] = row4[lane + 64];
      av[2] = row4[lane + 128]; av[3] = row4[lane + 192];
#pragma unroll
      for (int ci = 0; ci < 4; ++ci) {
        unsigned n = (unsigned)(av[ci].x != 0) | ((unsigned)(av[ci].y != 0) << 1) |
                     ((unsigned)(av[ci].z != 0) << 2) | ((unsigned)(av[ci].w != 0) << 3);
        unsigned d = (unsigned)(i - (ci * 256 + 4 * lane));
        if (d < 4u) n |= 1u << d;           // diagonal
        u64 val = (u64)n << (4 * m16);
#pragma unroll
        for (int msk = 1; msk <= 8; msk <<= 1)
          val |= (u64)__shfl_xor(val, msk, 64);
        words[ci] = val;
      }
    } else {                                // packed byte adjacency
      const unsigned* rowB = (const unsigned*)((const unsigned char*)adjv + ((size_t)b * NPTS + i) * NPTS);
      unsigned av[4];
      av[0] = rowB[lane]; av[1] = rowB[lane + 64];
      av[2] = rowB[lane + 128]; av[3] = rowB[lane + 192];
#pragma unroll
      for (int ci = 0; ci < 4; ++ci) {
        unsigned v = av[ci];
        unsigned n = ((v & 0xffu) ? 1u : 0u) | (((v >> 8) & 0xffu) ? 2u : 0u) |
                     (((v >> 16) & 0xffu) ? 4u : 0u) | ((v >> 24) ? 8u : 0u);
        unsigned d = (unsigned)(i - (ci * 256 + 4 * lane));
        if (d < 4u) n |= 1u << d;
        u64 val = (u64)n << (4 * m16);
#pragma unroll
        for (int msk = 1; msk <= 8; msk <<= 1)
          val |= (u64)__shfl_xor(val, msk, 64);
        words[ci] = val;
      }
    }
    if (m16 == 0) {
#pragma unroll
      for (int ci = 0; ci < 4; ++ci)
        abits[((size_t)b * NPTS + i) * 16 + ci * 4 + g] = words[ci];
    }
    return;
  }

  // ---------------- projection (frozen from the 47.7 us round) ----------------
  const int blk = blkAll;
  const int lane = t & 63;
  const int wv = t >> 6;
  const int it = blk & 15;
  const int hh = (blk >> 4) & 7;
  const int b  = blk >> 7;
  const int i0 = it * 64;
  const int bh = b * NH + hh;
  const int l15 = lane & 15;
  const int g4  = lane >> 4;
  const int koff = g4 * 8;

  const int o_t  = t >> 2;
  const int gsrc = (t & 3) ^ ((o_t >> 1) & 3);
  const unsigned short* gB_hi = wT_hi + ((size_t)(hh * FOUT + o_t)) * FIN + gsrc * 8;
  const unsigned short* gB_lo = wT_lo + ((size_t)(hh * FOUT + o_t)) * FIN + gsrc * 8;

  const float* arow = h + ((size_t)(b * NPTS + i0 + wv * 16 + l15)) * FIN + koff;

  const int sw = (l15 >> 1) & 3;
  int roff[4];
#pragma unroll
  for (int nt = 0; nt < 4; ++nt)
    roff[nt] = (nt * 16 + l15) * 32 + (g4 ^ sw) * 8;

  // prologue, per-group issue order [DMA_hi, DMA_lo, A0, A1] (4 VMEM ops)
  float4 hA[3][2];
  gl_lds16(gB_hi, &sm.Bbuf[0][wv * 512]);
  gl_lds16(gB_lo, &sm.Bbuf[0][2048 + wv * 512]);
  hA[0][0] = *(const float4*)(arow);
  hA[0][1] = *(const float4*)(arow + 4);
  __builtin_amdgcn_sched_barrier(0);
  gl_lds16(gB_hi + 32, &sm.Bbuf[1][wv * 512]);
  gl_lds16(gB_lo + 32, &sm.Bbuf[1][2048 + wv * 512]);
  hA[1][0] = *(const float4*)(arow + 32);
  hA[1][1] = *(const float4*)(arow + 36);

  f4v acc[4];
#pragma unroll
  for (int nt = 0; nt < 4; ++nt) acc[nt] = 0.0f;

#pragma unroll
  for (int k0 = 0; k0 < 8; ++k0) {
    if (k0 == 7) asm volatile("s_waitcnt vmcnt(0)" ::: "memory");
    else         asm volatile("s_waitcnt vmcnt(4)" ::: "memory");
    __builtin_amdgcn_sched_barrier(0);
    __builtin_amdgcn_s_barrier();        // all waves confirmed buf[k0] ready
    __builtin_amdgcn_sched_barrier(0);

    if (k0 < 6) {                        // issue k0+2 (buffer freed by barrier)
      const int nb = (k0 + 2) % 3;
      gl_lds16(gB_hi + (k0 + 2) * 32, &sm.Bbuf[nb][wv * 512]);
      gl_lds16(gB_lo + (k0 + 2) * 32, &sm.Bbuf[nb][2048 + wv * 512]);
      hA[nb][0] = *(const float4*)(arow + (k0 + 2) * 32);
      hA[nb][1] = *(const float4*)(arow + (k0 + 2) * 32 + 4);
    }
    __builtin_amdgcn_sched_barrier(0);

    const int cb = k0 % 3;
    float av[8] = {hA[cb][0].x, hA[cb][0].y, hA[cb][0].z, hA[cb][0].w,
                   hA[cb][1].x, hA[cb][1].y, hA[cb][1].z, hA[cb][1].w};
    s8v Ah, Al;
#pragma unroll
    for (int e = 0; e < 8; ++e) {
      unsigned u = __float_as_uint(av[e]);
      float r = av[e] - __uint_as_float(u & 0xffff0000u);
      Ah[e] = (short)(unsigned short)(u >> 16);
      Al[e] = (short)(unsigned short)(__float_as_uint(r) >> 16);
    }

    const unsigned short* fb = &sm.Bbuf[cb][0];
#pragma unroll
    for (int nt = 0; nt < 4; ++nt) {
      s8v Bh = *(const s8v*)(fb + roff[nt]);
      s8v Bl = *(const s8v*)(fb + 2048 + roff[nt]);
      acc[nt] = __builtin_amdgcn_mfma_f32_16x16x32_bf16(Ah, Bh, acc[nt], 0, 0, 0);
      acc[nt] = __builtin_amdgcn_mfma_f32_16x16x32_bf16(Al, Bh, acc[nt], 0, 0, 0);
      acc[nt] = __builtin_amdgcn_mfma_f32_16x16x32_bf16(Ah, Bl, acc[nt], 0, 0, 0);
    }
  }
  __syncthreads();   // all waves done reading Bbuf before tile overwrites it

  // ---- attn_src / attn_dst: tanh(hp) . a
  float a_s[4], a_d[4];
#pragma unroll
  for (int nt = 0; nt < 4; ++nt) {
    a_s[nt] = a_src[hh * FOUT + nt * 16 + l15];
    a_d[nt] = a_dst[hh * FOUT + nt * 16 + l15];
  }
#pragma unroll
  for (int qq = 0; qq < 4; ++qq) {
    float ps = 0.f, pd = 0.f;
#pragma unroll
    for (int nt = 0; nt < 4; ++nt) {
      float tv = fast_tanh(acc[nt][qq]);
      ps = fmaf(tv, a_s[nt], ps);
      pd = fmaf(tv, a_d[nt], pd);
    }
#pragma unroll
    for (int m = 8; m >= 1; m >>= 1) {
      ps += __shfl_xor(ps, m, 64);
      pd += __shfl_xor(pd, m, 64);
    }
    if (l15 == 0) {
      int row = i0 + wv * 16 + g4 * 4 + qq;
      srcb[(size_t)bh * NPTS + row] = ps;
      dstb[(size_t)bh * NPTS + row] = pd;
    }
  }

  // ---- transpose via LDS -> f16 fragment-major store
#pragma unroll
  for (int nt = 0; nt < 4; ++nt)
#pragma unroll
    for (int qq = 0; qq < 4; ++qq)
      sm.tile[wv * 16 + g4 * 4 + qq][nt * 16 + l15] = acc[nt][qq];
  __syncthreads();

  const int cbase = t >> 6;
#pragma unroll
  for (int ci = 0; ci < 2; ++ci) {
    int cc = cbase + ci * 4;          // cc = ks*4 + nt
    int ks = cc >> 2, nt2 = cc & 3;
    int jb = ks * 32 + ((lane >> 4) * 8);
    int ob = nt2 * 16 + l15;
    h8v v;
#pragma unroll
    for (int e = 0; e < 8; ++e) v[e] = (_Float16)sm.tile[jb + e][ob];
    *(h8v*)(hfrag + (((size_t)(bh * 16 + it) * 8 + cc) * 64 + lane) * 8) = v;
  }
}

// ---------------------------------------------------------------------------
// Fused masked softmax + PV, KVBLK=64, exp-free P phase:
// p = max(A_i*E1_j, B_i*E2_j); per-block tables E1,E2 (2048 exps) + per-row
// scalars A_i,B_i. Mask via 16-entry LUT AND. Denominator via P*ones MFMA.
// (Frozen from the 47.7 us round.)
// ---------------------------------------------------------------------------
__global__ __launch_bounds__(256, 4) void attn_kernel(
    const u64* __restrict__ abits,
    const unsigned short* __restrict__ hfrag,
    const float* __restrict__ srcb, const float* __restrict__ dstb,
    const float* __restrict__ bias, float* __restrict__ out)
{
  __shared__ float e1sh[NPTS];               // 2^(L2E*dst_j)
  __shared__ float e2sh[NPTS];               // 2^(0.2*L2E*dst_j)
  __shared__ float wred[4];
  __shared__ uint2 mlut[16];                 // 4 adjacency bits -> keep masks
  __shared__ unsigned short frag[2][4096];   // 2 x 8KB f16 fragment tiles

  const int t = threadIdx.x;
  const int lane = t & 63;
  const int wv = t >> 6;
  const int blk = blockIdx.x;
  const int it = blk & 15;
  const int hh = (blk >> 4) & 7;
  const int b  = blk >> 7;
  const int i0 = it * 64;
  const int bh = b * NH + hh;
  const int l15 = lane & 15;
  const int koff = (lane >> 4) * 8;
  const int rowA = i0 + wv * 16 + l15;

  const uint4* fgb = (const uint4*)hfrag + (size_t)bh * 16 * 512;
  const u64* abrow = abits + ((size_t)b * NPTS + rowA) * 16;

  uint4 s0 = fgb[t];
  uint4 s1 = fgb[t + 256];
  u64 ab_cur = abrow[0];
  const float src_r = srcb[(size_t)bh * NPTS + rowA];
  float4 dv = ((const float4*)(dstb + (size_t)bh * NPTS))[t];

  if (t < 16) {                              // all-ones/all-zeros keep masks
    unsigned m = t;
    mlut[t] = make_uint2(
        ((m & 1u) ? 0xFFFFu : 0u) | (((m >> 1) & 1u) ? 0xFFFF0000u : 0u),
        (((m >> 2) & 1u) ? 0xFFFFu : 0u) | (((m >> 3) & 1u) ? 0xFFFF0000u : 0u));
  }

  const float L2E = 1.44269504f;
  {
    float4 e1, e2;
    e1.x = hw_exp2(dv.x * L2E);          e1.y = hw_exp2(dv.y * L2E);
    e1.z = hw_exp2(dv.z * L2E);          e1.w = hw_exp2(dv.w * L2E);
    e2.x = hw_exp2(dv.x * (0.2f * L2E)); e2.y = hw_exp2(dv.y * (0.2f * L2E));
    e2.z = hw_exp2(dv.z * (0.2f * L2E)); e2.w = hw_exp2(dv.w * (0.2f * L2E));
    ((float4*)e1sh)[t] = e1;
    ((float4*)e2sh)[t] = e2;
  }
  float lm = fmaxf(fmaxf(dv.x, dv.y), fmaxf(dv.z, dv.w));
#pragma unroll
  for (int m = 32; m >= 1; m >>= 1) lm = fmaxf(lm, __shfl_xor(lm, m, 64));
  if (lane == 0) wred[wv] = lm;
  __syncthreads();
  const float M = fmaxf(fmaxf(wred[0], wred[1]), fmaxf(wred[2], wred[3]));
  const float xm = src_r + M;
  const float m_row = fmaxf(xm, 0.2f * xm);        // >= true row max (all j)
  const float Ai = hw_exp2((src_r - m_row) * L2E);
  const float Bi = hw_exp2((0.2f * src_r - m_row) * L2E);

  ((uint4*)&frag[0][0])[t]       = s0;
  ((uint4*)&frag[0][0])[t + 256] = s1;
  __syncthreads();

  h8v ones;
#pragma unroll
  for (int e = 0; e < 8; ++e) ones[e] = (_Float16)1.0f;

  f4v acc[4], acc_l;
#pragma unroll
  for (int nt = 0; nt < 4; ++nt) acc[nt] = 0.0f;
  acc_l = 0.0f;

#pragma unroll 2
  for (int jt = 0; jt < 16; ++jt) {
    const int buf = jt & 1;
    uint4 n0, n1; u64 ab_nxt;
    if (jt < 15) {
      const uint4* fgn = fgb + (size_t)(jt + 1) * 512;
      n0 = fgn[t];
      n1 = fgn[t + 256];
      ab_nxt = abrow[jt + 1];
    }
    __builtin_amdgcn_sched_barrier(0);       // pin staging loads above

    // ---- P phase (exp-free): p = max(Ai*E1, Bi*E2), mask via LUT-AND
    const int jb = jt * 64 + koff;
    float4 ea0 = *(const float4*)&e1sh[jb];
    float4 ea1 = *(const float4*)&e1sh[jb + 4];
    float4 eb0 = *(const float4*)&e2sh[jb];
    float4 eb1 = *(const float4*)&e2sh[jb + 4];
    float4 ec0 = *(const float4*)&e1sh[jb + 32];
    float4 ec1 = *(const float4*)&e1sh[jb + 36];
    float4 ed0 = *(const float4*)&e2sh[jb + 32];
    float4 ed1 = *(const float4*)&e2sh[jb + 36];
    float p0[8] = {
      fmaxf(Ai * ea0.x, Bi * eb0.x), fmaxf(Ai * ea0.y, Bi * eb0.y),
      fmaxf(Ai * ea0.z, Bi * eb0.z), fmaxf(Ai * ea0.w, Bi * eb0.w),
      fmaxf(Ai * ea1.x, Bi * eb1.x), fmaxf(Ai * ea1.y, Bi * eb1.y),
      fmaxf(Ai * ea1.z, Bi * eb1.z), fmaxf(Ai * ea1.w, Bi * eb1.w)};
    float p1[8] = {
      fmaxf(Ai * ec0.x, Bi * ed0.x), fmaxf(Ai * ec0.y, Bi * ed0.y),
      fmaxf(Ai * ec0.z, Bi * ed0.z), fmaxf(Ai * ec0.w, Bi * ed0.w),
      fmaxf(Ai * ec1.x, Bi * ed1.x), fmaxf(Ai * ec1.y, Bi * ed1.y),
      fmaxf(Ai * ec1.z, Bi * ed1.z), fmaxf(Ai * ec1.w, Bi * ed1.w)};
    const unsigned w0 = (unsigned)(ab_cur) >> koff;
    const unsigned w1 = (unsigned)(ab_cur >> 32) >> koff;
    union { fp16x2 q[4]; unsigned u[4]; h8v v; } ua, ub;
    ua.q[0] = __builtin_amdgcn_cvt_pkrtz(p0[0], p0[1]);
    ua.q[1] = __builtin_amdgcn_cvt_pkrtz(p0[2], p0[3]);
    ua.q[2] = __builtin_amdgcn_cvt_pkrtz(p0[4], p0[5]);
    ua.q[3] = __builtin_amdgcn_cvt_pkrtz(p0[6], p0[7]);
    ub.q[0] = __builtin_amdgcn_cvt_pkrtz(p1[0], p1[1]);
    ub.q[1] = __builtin_amdgcn_cvt_pkrtz(p1[2], p1[3]);
    ub.q[2] = __builtin_amdgcn_cvt_pkrtz(p1[4], p1[5]);
    ub.q[3] = __builtin_amdgcn_cvt_pkrtz(p1[6], p1[7]);
    {
      uint2 ma0 = mlut[w0 & 15], ma1 = mlut[(w0 >> 4) & 15];
      uint2 mb0 = mlut[w1 & 15], mb1 = mlut[(w1 >> 4) & 15];
      ua.u[0] &= ma0.x; ua.u[1] &= ma0.y; ua.u[2] &= ma1.x; ua.u[3] &= ma1.y;
      ub.u[0] &= mb0.x; ub.u[1] &= mb0.y; ub.u[2] &= mb1.x; ub.u[3] &= mb1.y;
    }
    h8v pa0 = ua.v;
    h8v pa1 = ub.v;

    // ---- MFMA phase (numerator + P*ones denominator)
    __builtin_amdgcn_s_setprio(1);
#pragma unroll
    for (int nt = 0; nt < 4; ++nt) {
      h8v B0 = *(const h8v*)&frag[buf][(nt * 64 + lane) * 8];
      acc[nt] = __builtin_amdgcn_mfma_f32_16x16x32_f16(pa0, B0, acc[nt], 0, 0, 0);
    }
    acc_l = __builtin_amdgcn_mfma_f32_16x16x32_f16(pa0, ones, acc_l, 0, 0, 0);
#pragma unroll
    for (int nt = 0; nt < 4; ++nt) {
      h8v B1 = *(const h8v*)&frag[buf][((4 + nt) * 64 + lane) * 8];
      acc[nt] = __builtin_amdgcn_mfma_f32_16x16x32_f16(pa1, B1, acc[nt], 0, 0, 0);
    }
    acc_l = __builtin_amdgcn_mfma_f32_16x16x32_f16(pa1, ones, acc_l, 0, 0, 0);
    __builtin_amdgcn_s_setprio(0);

    if (jt < 15) {
      ((uint4*)&frag[buf ^ 1][0])[t]       = n0;
      ((uint4*)&frag[buf ^ 1][0])[t + 256] = n1;
      ab_cur = ab_nxt;
    }
    __syncthreads();
  }

  // ---- epilogue: denominator already per-row in acc_l (C-layout matches acc)
  float bias4[4];
#pragma unroll
  for (int nt = 0; nt < 4; ++nt) bias4[nt] = bias[nt * 16 + l15];

#pragma unroll
  for (int qq = 0; qq < 4; ++qq) {
    float linv = 1.0f / acc_l[qq];
    int rowq = i0 + wv * 16 + (lane >> 4) * 4 + qq;
    size_t ob = ((size_t)bh * NPTS + rowq) * FOUT;
#pragma unroll
    for (int nt = 0; nt < 4; ++nt)
      out[ob + nt * 16 + l15] = acc[nt][qq] * linv + bias4[nt];
  }
}

// ---------------------------------------------------------------------------
extern "C" void kernel_launch(void* const* d_in, const int* in_sizes, int n_in,
                              void* d_out, int out_size, void* d_ws, size_t ws_size,
                              hipStream_t stream)
{
  const float* h     = (const float*)d_in[0];
  const void*  adj   = d_in[1];
  const float* w     = (const float*)d_in[2];
  const float* a_src = (const float*)d_in[3];
  const float* a_dst = (const float*)d_in[4];
  const float* bias  = (const float*)d_in[5];
  float* out = (float*)d_out;

  // ws layout (16B aligned), ~10.9 MB total
  char* p = (char*)d_ws;
  float* srcb = (float*)p;                      p += (size_t)BS * NH * NPTS * 4;
  float* dstb = (float*)p;                      p += (size_t)BS * NH * NPTS * 4;
  unsigned short* wT_hi = (unsigned short*)p;   p += (size_t)NH * FOUT * FIN * 2;
  unsigned short* wT_lo = (unsigned short*)p;   p += (size_t)NH * FOUT * FIN * 2;
  u64* abits = (u64*)p;                         p += (size_t)BS * NPTS * 16 * 8;
  unsigned short* hfrag = (unsigned short*)p;

  wsplit_kernel<<<dim3(64), dim3(256), 0, stream>>>(w, wT_hi, wT_lo);
  projpack_kernel<<<dim3(3072), dim3(256), 0, stream>>>(
      h, adj, wT_hi, wT_lo, a_src, a_dst, abits, hfrag, srcb, dstb);
  attn_kernel<<<dim3(1024), dim3(256), 0, stream>>>(
      abits, hfrag, srcb, dstb, bias, out);
}

// Round 19
// 47.567 us; speedup vs baseline: 1.0116x; 1.0116x over previous
//
#include <hip/hip_runtime.h>
#include <math.h>

#define BS 8
#define NPTS 1024
#define NH 8
#define FIN 256
#define FOUT 64

typedef __attribute__((ext_vector_type(8))) short s8v;       // 8 bf16
typedef __attribute__((ext_vector_type(8))) _Float16 h8v;    // 8 f16
typedef __attribute__((ext_vector_type(2))) __fp16 fp16x2;   // cvt_pkrtz result
typedef __attribute__((ext_vector_type(4))) float f4v;       // 4 f32 acc
typedef unsigned long long u64;

__device__ __forceinline__ unsigned short f2bf(float f) {
  unsigned u = __float_as_uint(f);
  return (unsigned short)((u + 0x7fffu + ((u >> 16) & 1u)) >> 16);
}
__device__ __forceinline__ float bf2f(unsigned short s) {
  return __uint_as_float(((unsigned)s) << 16);
}
__device__ __forceinline__ float fast_tanh(float x) {
  float e = __expf(2.f * x);
  return 1.f - 2.f / (e + 1.f);
}
__device__ __forceinline__ float hw_exp2(float x) {   // D = 2^x (v_exp_f32)
  float r;
  asm("v_exp_f32 %0, %1" : "=v"(r) : "v"(x));
  return r;
}

// async global->LDS DMA, 16B per lane; LDS dest = wave-uniform base + lane*16
__device__ __forceinline__ void gl_lds16(const void* g, void* l) {
  __builtin_amdgcn_global_load_lds(
      (const __attribute__((address_space(1))) unsigned*)g,
      (__attribute__((address_space(3))) unsigned*)l, 16, 0, 0);
}

// ---------------------------------------------------------------------------
// prep: blocks 0..2047   = adj -> bitmask pack (diag folded in)
//       blocks 2048..2111 = w -> wT_hi/lo bf16 split ([h][o][k])
// ---------------------------------------------------------------------------
__global__ __launch_bounds__(256) void prep_kernel(
    const void* __restrict__ adjv, const float* __restrict__ w,
    u64* __restrict__ abits,
    unsigned short* __restrict__ wT_hi, unsigned short* __restrict__ wT_lo)
{
  const int blk = blockIdx.x;
  const int t = threadIdx.x;
  if (blk < 2048) {
    __shared__ int badsh;
    if (t == 0) badsh = 0;
    __syncthreads();
    if (((const unsigned*)adjv)[t] > 1u) badsh = 1;   // dtype detect (1KB scan)
    __syncthreads();
    const int lane = t & 63;
    const int gw = blk * 4 + (t >> 6);                // row id 0..8191
    const int b = gw >> 10, i = gw & 1023;
    const int m16 = lane & 15, g = lane >> 4;
    u64 words[4];
    if (badsh == 0) {                                 // int32 {0,1} adjacency
      const int4* row4 = (const int4*)((const int*)adjv + ((size_t)b * NPTS + i) * NPTS);
      int4 av[4];
      av[0] = row4[lane]; av[1] = row4[lane + 64];
      av[2] = row4[lane + 128]; av[3] = row4[lane + 192];
#pragma unroll
      for (int ci = 0; ci < 4; ++ci) {
        unsigned n = (unsigned)(av[ci].x != 0) | ((unsigned)(av[ci].y != 0) << 1) |
                     ((unsigned)(av[ci].z != 0) << 2) | ((unsigned)(av[ci].w != 0) << 3);
        unsigned d = (unsigned)(i - (ci * 256 + 4 * lane));
        if (d < 4u) n |= 1u << d;                     // diagonal
        u64 val = (u64)n << (4 * m16);
#pragma unroll
        for (int msk = 1; msk <= 8; msk <<= 1)
          val |= (u64)__shfl_xor(val, msk, 64);
        words[ci] = val;
      }
    } else {                                          // packed byte adjacency
      const unsigned* rowB = (const unsigned*)((const unsigned char*)adjv + ((size_t)b * NPTS + i) * NPTS);
      unsigned av[4];
      av[0] = rowB[lane]; av[1] = rowB[lane + 64];
      av[2] = rowB[lane + 128]; av[3] = rowB[lane + 192];
#pragma unroll
      for (int ci = 0; ci < 4; ++ci) {
        unsigned v = av[ci];
        unsigned n = ((v & 0xffu) ? 1u : 0u) | (((v >> 8) & 0xffu) ? 2u : 0u) |
                     (((v >> 16) & 0xffu) ? 4u : 0u) | ((v >> 24) ? 8u : 0u);
        unsigned d = (unsigned)(i - (ci * 256 + 4 * lane));
        if (d < 4u) n |= 1u << d;
        u64 val = (u64)n << (4 * m16);
#pragma unroll
        for (int msk = 1; msk <= 8; msk <<= 1)
          val |= (u64)__shfl_xor(val, msk, 64);
        words[ci] = val;
      }
    }
    if (m16 == 0) {
#pragma unroll
      for (int ci = 0; ci < 4; ++ci)
        abits[((size_t)b * NPTS + i) * 16 + ci * 4 + g] = words[ci];
    }
  } else {
    const int bb = blk - 2048;
    const int hh = bb >> 3, ks = bb & 7;
    const int o = t & 63, kq = t >> 6;
#pragma unroll
    for (int e = 0; e < 8; ++e) {
      int k = ks * 32 + kq * 8 + e;
      float v = w[((size_t)hh * FIN + k) * FOUT + o];
      unsigned short hi = f2bf(v);
      wT_hi[((size_t)hh * FOUT + o) * FIN + k] = hi;
      wT_lo[((size_t)hh * FOUT + o) * FIN + k] = f2bf(v - bf2f(hi));
    }
  }
}

// ---------------------------------------------------------------------------
// Projection via MFMA (3-term bf16 split ~ f32 precision), counted-vmcnt
// pipeline: 3-buffer LDS ring, W-tile DMA + f32 A-loads issued 2 k-steps
// ahead (4 VMEM ops/group), per-step s_waitcnt vmcnt(4) + raw s_barrier.
// A split (truncation) done in-register at use — same bytes as pre-split.
// ---------------------------------------------------------------------------
union ProjSmem {
  unsigned short Bbuf[3][4096];   // 3 x 8KB: [hi 2048 el | lo 2048 el]
  float tile[64][65];             // epilogue transpose (reused storage)
};

__global__ __launch_bounds__(256, 4) void proj_kernel(
    const float* __restrict__ h,
    const unsigned short* __restrict__ wT_hi, const unsigned short* __restrict__ wT_lo,
    const float* __restrict__ a_src, const float* __restrict__ a_dst,
    unsigned short* __restrict__ hfrag,
    float* __restrict__ srcb, float* __restrict__ dstb)
{
  __shared__ ProjSmem sm;

  const int t = threadIdx.x;
  const int lane = t & 63;
  const int wv = t >> 6;
  const int blk = blockIdx.x;
  const int it = blk & 15;
  const int hh = (blk >> 4) & 7;
  const int b  = blk >> 7;
  const int i0 = it * 64;
  const int bh = b * NH + hh;
  const int l15 = lane & 15;
  const int g4  = lane >> 4;
  const int koff = g4 * 8;

  const int o_t  = t >> 2;
  const int gsrc = (t & 3) ^ ((o_t >> 1) & 3);
  const unsigned short* gB_hi = wT_hi + ((size_t)(hh * FOUT + o_t)) * FIN + gsrc * 8;
  const unsigned short* gB_lo = wT_lo + ((size_t)(hh * FOUT + o_t)) * FIN + gsrc * 8;

  const float* arow = h + ((size_t)(b * NPTS + i0 + wv * 16 + l15)) * FIN + koff;

  const int sw = (l15 >> 1) & 3;
  int roff[4];
#pragma unroll
  for (int nt = 0; nt < 4; ++nt)
    roff[nt] = (nt * 16 + l15) * 32 + (g4 ^ sw) * 8;

  // prologue, per-group issue order [DMA_hi, DMA_lo, A0, A1] (4 VMEM ops)
  float4 hA[3][2];
  gl_lds16(gB_hi, &sm.Bbuf[0][wv * 512]);
  gl_lds16(gB_lo, &sm.Bbuf[0][2048 + wv * 512]);
  hA[0][0] = *(const float4*)(arow);
  hA[0][1] = *(const float4*)(arow + 4);
  __builtin_amdgcn_sched_barrier(0);
  gl_lds16(gB_hi + 32, &sm.Bbuf[1][wv * 512]);
  gl_lds16(gB_lo + 32, &sm.Bbuf[1][2048 + wv * 512]);
  hA[1][0] = *(const float4*)(arow + 32);
  hA[1][1] = *(const float4*)(arow + 36);

  f4v acc[4];
#pragma unroll
  for (int nt = 0; nt < 4; ++nt) acc[nt] = 0.0f;

#pragma unroll
  for (int k0 = 0; k0 < 8; ++k0) {
    // retire group k0 (2 DMA + 2 A-loads); keep later groups in flight
    if (k0 == 7) asm volatile("s_waitcnt vmcnt(0)" ::: "memory");
    else         asm volatile("s_waitcnt vmcnt(4)" ::: "memory");
    __builtin_amdgcn_sched_barrier(0);
    __builtin_amdgcn_s_barrier();        // all waves confirmed buf[k0] ready
    __builtin_amdgcn_sched_barrier(0);

    if (k0 < 6) {                        // issue k0+2 (buffer freed by barrier)
      const int nb = (k0 + 2) % 3;
      gl_lds16(gB_hi + (k0 + 2) * 32, &sm.Bbuf[nb][wv * 512]);
      gl_lds16(gB_lo + (k0 + 2) * 32, &sm.Bbuf[nb][2048 + wv * 512]);
      hA[nb][0] = *(const float4*)(arow + (k0 + 2) * 32);
      hA[nb][1] = *(const float4*)(arow + (k0 + 2) * 32 + 4);
    }
    __builtin_amdgcn_sched_barrier(0);

    const int cb = k0 % 3;
    // in-register truncation split of the f32 A fragment
    float av[8] = {hA[cb][0].x, hA[cb][0].y, hA[cb][0].z, hA[cb][0].w,
                   hA[cb][1].x, hA[cb][1].y, hA[cb][1].z, hA[cb][1].w};
    s8v Ah, Al;
#pragma unroll
    for (int e = 0; e < 8; ++e) {
      unsigned u = __float_as_uint(av[e]);
      float r = av[e] - __uint_as_float(u & 0xffff0000u);
      Ah[e] = (short)(unsigned short)(u >> 16);
      Al[e] = (short)(unsigned short)(__float_as_uint(r) >> 16);
    }

    const unsigned short* fb = &sm.Bbuf[cb][0];
#pragma unroll
    for (int nt = 0; nt < 4; ++nt) {
      s8v Bh = *(const s8v*)(fb + roff[nt]);
      s8v Bl = *(const s8v*)(fb + 2048 + roff[nt]);
      acc[nt] = __builtin_amdgcn_mfma_f32_16x16x32_bf16(Ah, Bh, acc[nt], 0, 0, 0);
      acc[nt] = __builtin_amdgcn_mfma_f32_16x16x32_bf16(Al, Bh, acc[nt], 0, 0, 0);
      acc[nt] = __builtin_amdgcn_mfma_f32_16x16x32_bf16(Ah, Bl, acc[nt], 0, 0, 0);
    }
  }
  __syncthreads();   // all waves done reading Bbuf before tile overwrites it

  // ---- attn_src / attn_dst: tanh(hp) . a
  float a_s[4], a_d[4];
#pragma unroll
  for (int nt = 0; nt < 4; ++nt) {
    a_s[nt] = a_src[hh * FOUT + nt * 16 + l15];
    a_d[nt] = a_dst[hh * FOUT + nt * 16 + l15];
  }
#pragma unroll
  for (int qq = 0; qq < 4; ++qq) {
    float ps = 0.f, pd = 0.f;
#pragma unroll
    for (int nt = 0; nt < 4; ++nt) {
      float tv = fast_tanh(acc[nt][qq]);
      ps = fmaf(tv, a_s[nt], ps);
      pd = fmaf(tv, a_d[nt], pd);
    }
#pragma unroll
    for (int m = 8; m >= 1; m >>= 1) {
      ps += __shfl_xor(ps, m, 64);
      pd += __shfl_xor(pd, m, 64);
    }
    if (l15 == 0) {
      int row = i0 + wv * 16 + g4 * 4 + qq;
      srcb[(size_t)bh * NPTS + row] = ps;
      dstb[(size_t)bh * NPTS + row] = pd;
    }
  }

  // ---- transpose via LDS -> f16 fragment-major store
#pragma unroll
  for (int nt = 0; nt < 4; ++nt)
#pragma unroll
    for (int qq = 0; qq < 4; ++qq)
      sm.tile[wv * 16 + g4 * 4 + qq][nt * 16 + l15] = acc[nt][qq];
  __syncthreads();

  const int cbase = t >> 6;
#pragma unroll
  for (int ci = 0; ci < 2; ++ci) {
    int cc = cbase + ci * 4;          // cc = ks*4 + nt
    int ks = cc >> 2, nt2 = cc & 3;
    int jb = ks * 32 + ((lane >> 4) * 8);
    int ob = nt2 * 16 + l15;
    h8v v;
#pragma unroll
    for (int e = 0; e < 8; ++e) v[e] = (_Float16)sm.tile[jb + e][ob];
    *(h8v*)(hfrag + (((size_t)(bh * 16 + it) * 8 + cc) * 64 + lane) * 8) = v;
  }
}

// ---------------------------------------------------------------------------
// Fused masked softmax + PV, KVBLK=64, exp-free P phase:
// p = max(A_i*E1_j, B_i*E2_j); per-block tables E1,E2 (2048 exps) + per-row
// scalars A_i,B_i. Mask via 16-entry LUT AND. Denominator via P*ones MFMA.
// ---------------------------------------------------------------------------
__global__ __launch_bounds__(256, 4) void attn_kernel(
    const u64* __restrict__ abits,
    const unsigned short* __restrict__ hfrag,
    const float* __restrict__ srcb, const float* __restrict__ dstb,
    const float* __restrict__ bias, float* __restrict__ out)
{
  __shared__ float e1sh[NPTS];               // 2^(L2E*dst_j)
  __shared__ float e2sh[NPTS];               // 2^(0.2*L2E*dst_j)
  __shared__ float wred[4];
  __shared__ uint2 mlut[16];                 // 4 adjacency bits -> keep masks
  __shared__ unsigned short frag[2][4096];   // 2 x 8KB f16 fragment tiles

  const int t = threadIdx.x;
  const int lane = t & 63;
  const int wv = t >> 6;
  const int blk = blockIdx.x;
  const int it = blk & 15;
  const int hh = (blk >> 4) & 7;
  const int b  = blk >> 7;
  const int i0 = it * 64;
  const int bh = b * NH + hh;
  const int l15 = lane & 15;
  const int koff = (lane >> 4) * 8;
  const int rowA = i0 + wv * 16 + l15;

  const uint4* fgb = (const uint4*)hfrag + (size_t)bh * 16 * 512;
  const u64* abrow = abits + ((size_t)b * NPTS + rowA) * 16;

  uint4 s0 = fgb[t];
  uint4 s1 = fgb[t + 256];
  u64 ab_cur = abrow[0];
  const float src_r = srcb[(size_t)bh * NPTS + rowA];
  float4 dv = ((const float4*)(dstb + (size_t)bh * NPTS))[t];

  if (t < 16) {                              // all-ones/all-zeros keep masks
    unsigned m = t;
    mlut[t] = make_uint2(
        ((m & 1u) ? 0xFFFFu : 0u) | (((m >> 1) & 1u) ? 0xFFFF0000u : 0u),
        (((m >> 2) & 1u) ? 0xFFFFu : 0u) | (((m >> 3) & 1u) ? 0xFFFF0000u : 0u));
  }

  const float L2E = 1.44269504f;
  {
    float4 e1, e2;
    e1.x = hw_exp2(dv.x * L2E);          e1.y = hw_exp2(dv.y * L2E);
    e1.z = hw_exp2(dv.z * L2E);          e1.w = hw_exp2(dv.w * L2E);
    e2.x = hw_exp2(dv.x * (0.2f * L2E)); e2.y = hw_exp2(dv.y * (0.2f * L2E));
    e2.z = hw_exp2(dv.z * (0.2f * L2E)); e2.w = hw_exp2(dv.w * (0.2f * L2E));
    ((float4*)e1sh)[t] = e1;
    ((float4*)e2sh)[t] = e2;
  }
  float lm = fmaxf(fmaxf(dv.x, dv.y), fmaxf(dv.z, dv.w));
#pragma unroll
  for (int m = 32; m >= 1; m >>= 1) lm = fmaxf(lm, __shfl_xor(lm, m, 64));
  if (lane == 0) wred[wv] = lm;
  __syncthreads();
  const float M = fmaxf(fmaxf(wred[0], wred[1]), fmaxf(wred[2], wred[3]));
  const float xm = src_r + M;
  const float m_row = fmaxf(xm, 0.2f * xm);        // >= true row max (all j)
  const float Ai = hw_exp2((src_r - m_row) * L2E);
  const float Bi = hw_exp2((0.2f * src_r - m_row) * L2E);

  ((uint4*)&frag[0][0])[t]       = s0;
  ((uint4*)&frag[0][0])[t + 256] = s1;
  __syncthreads();

  h8v ones;
#pragma unroll
  for (int e = 0; e < 8; ++e) ones[e] = (_Float16)1.0f;

  f4v acc[4], acc_l;
#pragma unroll
  for (int nt = 0; nt < 4; ++nt) acc[nt] = 0.0f;
  acc_l = 0.0f;

#pragma unroll 2
  for (int jt = 0; jt < 16; ++jt) {
    const int buf = jt & 1;
    uint4 n0, n1; u64 ab_nxt;
    if (jt < 15) {
      const uint4* fgn = fgb + (size_t)(jt + 1) * 512;
      n0 = fgn[t];
      n1 = fgn[t + 256];
      ab_nxt = abrow[jt + 1];
    }
    __builtin_amdgcn_sched_barrier(0);       // pin staging loads above

    // ---- P phase (exp-free): p = max(Ai*E1, Bi*E2), mask via LUT-AND
    const int jb = jt * 64 + koff;
    float4 ea0 = *(const float4*)&e1sh[jb];
    float4 ea1 = *(const float4*)&e1sh[jb + 4];
    float4 eb0 = *(const float4*)&e2sh[jb];
    float4 eb1 = *(const float4*)&e2sh[jb + 4];
    float4 ec0 = *(const float4*)&e1sh[jb + 32];
    float4 ec1 = *(const float4*)&e1sh[jb + 36];
    float4 ed0 = *(const float4*)&e2sh[jb + 32];
    float4 ed1 = *(const float4*)&e2sh[jb + 36];
    float p0[8] = {
      fmaxf(Ai * ea0.x, Bi * eb0.x), fmaxf(Ai * ea0.y, Bi * eb0.y),
      fmaxf(Ai * ea0.z, Bi * eb0.z), fmaxf(Ai * ea0.w, Bi * eb0.w),
      fmaxf(Ai * ea1.x, Bi * eb1.x), fmaxf(Ai * ea1.y, Bi * eb1.y),
      fmaxf(Ai * ea1.z, Bi * eb1.z), fmaxf(Ai * ea1.w, Bi * eb1.w)};
    float p1[8] = {
      fmaxf(Ai * ec0.x, Bi * ed0.x), fmaxf(Ai * ec0.y, Bi * ed0.y),
      fmaxf(Ai * ec0.z, Bi * ed0.z), fmaxf(Ai * ec0.w, Bi * ed0.w),
      fmaxf(Ai * ec1.x, Bi * ed1.x), fmaxf(Ai * ec1.y, Bi * ed1.y),
      fmaxf(Ai * ec1.z, Bi * ed1.z), fmaxf(Ai * ec1.w, Bi * ed1.w)};
    const unsigned w0 = (unsigned)(ab_cur) >> koff;
    const unsigned w1 = (unsigned)(ab_cur >> 32) >> koff;
    union { fp16x2 q[4]; unsigned u[4]; h8v v; } ua, ub;
    ua.q[0] = __builtin_amdgcn_cvt_pkrtz(p0[0], p0[1]);
    ua.q[1] = __builtin_amdgcn_cvt_pkrtz(p0[2], p0[3]);
    ua.q[2] = __builtin_amdgcn_cvt_pkrtz(p0[4], p0[5]);
    ua.q[3] = __builtin_amdgcn_cvt_pkrtz(p0[6], p0[7]);
    ub.q[0] = __builtin_amdgcn_cvt_pkrtz(p1[0], p1[1]);
    ub.q[1] = __builtin_amdgcn_cvt_pkrtz(p1[2], p1[3]);
    ub.q[2] = __builtin_amdgcn_cvt_pkrtz(p1[4], p1[5]);
    ub.q[3] = __builtin_amdgcn_cvt_pkrtz(p1[6], p1[7]);
    {
      uint2 ma0 = mlut[w0 & 15], ma1 = mlut[(w0 >> 4) & 15];
      uint2 mb0 = mlut[w1 & 15], mb1 = mlut[(w1 >> 4) & 15];
      ua.u[0] &= ma0.x; ua.u[1] &= ma0.y; ua.u[2] &= ma1.x; ua.u[3] &= ma1.y;
      ub.u[0] &= mb0.x; ub.u[1] &= mb0.y; ub.u[2] &= mb1.x; ub.u[3] &= mb1.y;
    }
    h8v pa0 = ua.v;
    h8v pa1 = ub.v;

    // ---- MFMA phase (numerator + P*ones denominator)
    __builtin_amdgcn_s_setprio(1);
#pragma unroll
    for (int nt = 0; nt < 4; ++nt) {
      h8v B0 = *(const h8v*)&frag[buf][(nt * 64 + lane) * 8];
      acc[nt] = __builtin_amdgcn_mfma_f32_16x16x32_f16(pa0, B0, acc[nt], 0, 0, 0);
    }
    acc_l = __builtin_amdgcn_mfma_f32_16x16x32_f16(pa0, ones, acc_l, 0, 0, 0);
#pragma unroll
    for (int nt = 0; nt < 4; ++nt) {
      h8v B1 = *(const h8v*)&frag[buf][((4 + nt) * 64 + lane) * 8];
      acc[nt] = __builtin_amdgcn_mfma_f32_16x16x32_f16(pa1, B1, acc[nt], 0, 0, 0);
    }
    acc_l = __builtin_amdgcn_mfma_f32_16x16x32_f16(pa1, ones, acc_l, 0, 0, 0);
    __builtin_amdgcn_s_setprio(0);

    if (jt < 15) {
      ((uint4*)&frag[buf ^ 1][0])[t]       = n0;
      ((uint4*)&frag[buf ^ 1][0])[t + 256] = n1;
      ab_cur = ab_nxt;
    }
    __syncthreads();
  }

  // ---- epilogue: denominator already per-row in acc_l (C-layout matches acc)
  float bias4[4];
#pragma unroll
  for (int nt = 0; nt < 4; ++nt) bias4[nt] = bias[nt * 16 + l15];

#pragma unroll
  for (int qq = 0; qq < 4; ++qq) {
    float linv = 1.0f / acc_l[qq];
    int rowq = i0 + wv * 16 + (lane >> 4) * 4 + qq;
    size_t ob = ((size_t)bh * NPTS + rowq) * FOUT;
#pragma unroll
    for (int nt = 0; nt < 4; ++nt)
      out[ob + nt * 16 + l15] = acc[nt][qq] * linv + bias4[nt];
  }
}

// ---------------------------------------------------------------------------
extern "C" void kernel_launch(void* const* d_in, const int* in_sizes, int n_in,
                              void* d_out, int out_size, void* d_ws, size_t ws_size,
                              hipStream_t stream)
{
  const float* h     = (const float*)d_in[0];
  const void*  adj   = d_in[1];
  const float* w     = (const float*)d_in[2];
  const float* a_src = (const float*)d_in[3];
  const float* a_dst = (const float*)d_in[4];
  const float* bias  = (const float*)d_in[5];
  float* out = (float*)d_out;

  // ws layout (16B aligned), ~10.9 MB total
  char* p = (char*)d_ws;
  float* srcb = (float*)p;                      p += (size_t)BS * NH * NPTS * 4;
  float* dstb = (float*)p;                      p += (size_t)BS * NH * NPTS * 4;
  unsigned short* wT_hi = (unsigned short*)p;   p += (size_t)NH * FOUT * FIN * 2;
  unsigned short* wT_lo = (unsigned short*)p;   p += (size_t)NH * FOUT * FIN * 2;
  u64* abits = (u64*)p;                         p += (size_t)BS * NPTS * 16 * 8;
  unsigned short* hfrag = (unsigned short*)p;

  prep_kernel<<<dim3(2112), dim3(256), 0, stream>>>(adj, w, abits, wT_hi, wT_lo);
  proj_kernel<<<dim3(1024), dim3(256), 0, stream>>>(
      h, wT_hi, wT_lo, a_src, a_dst, hfrag, srcb, dstb);
  attn_kernel<<<dim3(1024), dim3(256), 0, stream>>>(
      abits, hfrag, srcb, dstb, bias, out);
}